// Round 1
// baseline (488.840 us; speedup 1.0000x reference)
//
#include <hip/hip_runtime.h>
#include <stdint.h>

#define B_DIM 8192
#define DIN   2048
#define DOUT  8192

typedef int  v4i __attribute__((ext_vector_type(4)));
typedef char c8  __attribute__((ext_vector_type(8)));

__device__ __forceinline__ void gload_lds16(const void* g, void* l) {
  __builtin_amdgcn_global_load_lds(
      (const __attribute__((address_space(1))) void*)g,
      (__attribute__((address_space(3))) void*)l, 16, 0, 0);
}

__device__ __forceinline__ float wave_max(float m) {
#pragma unroll
  for (int off = 32; off; off >>= 1) m = fmaxf(m, __shfl_xor(m, off, 64));
  return m;
}

// ---- kernel 0: zero the two atomic absmax words ----
__global__ void k_init(unsigned int* p) {
  p[0] = 0u;
  p[1] = 0u;
}

// ---- kernel 1: global absmax of x ----
__global__ void k_absmax(const float4* __restrict__ x, int n4,
                         unsigned int* __restrict__ out_bits) {
  int idx = blockIdx.x * blockDim.x + threadIdx.x;
  int stride = gridDim.x * blockDim.x;
  float m = 0.f;
  for (int i = idx; i < n4; i += stride) {
    float4 v = x[i];
    m = fmaxf(m, fabsf(v.x));
    m = fmaxf(m, fabsf(v.y));
    m = fmaxf(m, fabsf(v.z));
    m = fmaxf(m, fabsf(v.w));
  }
  m = wave_max(m);
  if ((threadIdx.x & 63) == 0) atomicMax(out_bits, __float_as_uint(m));
}

// ---- kernel 2: quantize x to int8 (8 elems/thread) ----
__global__ void k_quant_x(const float* __restrict__ x, c8* __restrict__ xq,
                          int n8, const unsigned int* __restrict__ sa_bits) {
  int i = blockIdx.x * blockDim.x + threadIdx.x;
  if (i >= n8) return;
  float s_a = __uint_as_float(*sa_bits) / 127.0f;
  const float4* p = (const float4*)(x + (size_t)i * 8);
  float4 v0 = p[0], v1 = p[1];
  float vv[8] = {v0.x, v0.y, v0.z, v0.w, v1.x, v1.y, v1.z, v1.w};
  c8 q;
#pragma unroll
  for (int j = 0; j < 8; ++j) {
    float r = fminf(fmaxf(rintf(vv[j] / s_a), -127.f), 127.f);
    q[j] = (char)(int)r;
  }
  xq[i] = q;
}

// ---- kernel 3: per-row weight absmax + quantize (1 block / row) ----
__global__ __launch_bounds__(256) void k_quant_w(const float* __restrict__ w,
                                                 c8* __restrict__ wq,
                                                 float* __restrict__ s_w) {
  int row = blockIdx.x;
  int tid = threadIdx.x;
  const float4* wr = (const float4*)(w + (size_t)row * DIN);
  float4 v0 = wr[tid * 2], v1 = wr[tid * 2 + 1];
  float vv[8] = {v0.x, v0.y, v0.z, v0.w, v1.x, v1.y, v1.z, v1.w};
  float m = 0.f;
#pragma unroll
  for (int j = 0; j < 8; ++j) m = fmaxf(m, fabsf(vv[j]));
  m = wave_max(m);
  __shared__ float wmax[4];
  if ((tid & 63) == 0) wmax[tid >> 6] = m;
  __syncthreads();
  m = fmaxf(fmaxf(wmax[0], wmax[1]), fmaxf(wmax[2], wmax[3]));
  float s = m / 127.0f;
  if (tid == 0) s_w[row] = s;
  c8 q;
#pragma unroll
  for (int j = 0; j < 8; ++j) {
    float r = fminf(fmaxf(rintf(vv[j] / s), -127.f), 127.f);
    q[j] = (char)(int)r;
  }
  wq[(size_t)row * (DIN / 8) + tid] = q;
}

// ---- kernel 4: int8 GEMM (m97 structure) + dequant/bias epilogue + absmax ----
__global__ __launch_bounds__(256) void k_gemm(
    const char* __restrict__ Aq, const char* __restrict__ Bq,
    const float* __restrict__ s_w, const float* __restrict__ bias,
    const unsigned int* __restrict__ sa_bits, float* __restrict__ out,
    unsigned int* __restrict__ omax_bits) {
  __shared__ __align__(16) char As[128 * 64];
  __shared__ __align__(16) char Bs[128 * 64];

  const int tid = threadIdx.x;
  const int lane = tid & 63;
  const int wave = tid >> 6;
  const int wm = wave >> 1, wn = wave & 1;
  const int row0 = blockIdx.y * 128;
  const int col0 = blockIdx.x * 128;

  // staging: thread t covers As/Bs bytes [t*16, t*16+16) (chunk 0) and +4096 (chunk 1)
  const int srow = tid >> 2;       // 0..63
  const int skb = (tid & 3) * 16;  // k-byte offset
  const char* aSrc0 = Aq + (size_t)(row0 + srow) * DIN + skb;
  const char* aSrc1 = Aq + (size_t)(row0 + 64 + srow) * DIN + skb;
  const char* bSrc0 = Bq + (size_t)(col0 + srow) * DIN + skb;
  const char* bSrc1 = Bq + (size_t)(col0 + 64 + srow) * DIN + skb;
  char* aDst0 = &As[tid * 16];
  char* aDst1 = &As[4096 + tid * 16];
  char* bDst0 = &Bs[tid * 16];
  char* bDst1 = &Bs[4096 + tid * 16];

  v4i acc[4][4];
#pragma unroll
  for (int m = 0; m < 4; ++m)
#pragma unroll
    for (int n = 0; n < 4; ++n) acc[m][n] = (v4i){0, 0, 0, 0};

  const int fr = lane & 15;         // row/col within 16x16 fragment
  const int kg = (lane >> 4) * 16;  // k-byte group for this lane

  for (int kt = 0; kt < DIN; kt += 64) {
    __syncthreads();  // previous iteration's ds_reads done before overwrite
    gload_lds16(aSrc0 + kt, aDst0);
    gload_lds16(aSrc1 + kt, aDst1);
    gload_lds16(bSrc0 + kt, bDst0);
    gload_lds16(bSrc1 + kt, bDst1);
    __syncthreads();  // drains vmcnt(0): LDS tiles ready

    v4i a[4], b[4];
#pragma unroll
    for (int m = 0; m < 4; ++m)
      a[m] = *(const v4i*)&As[(wm * 64 + m * 16 + fr) * 64 + kg];
#pragma unroll
    for (int n = 0; n < 4; ++n)
      b[n] = *(const v4i*)&Bs[(wn * 64 + n * 16 + fr) * 64 + kg];
#pragma unroll
    for (int m = 0; m < 4; ++m)
#pragma unroll
      for (int n = 0; n < 4; ++n)
        acc[m][n] =
            __builtin_amdgcn_mfma_i32_16x16x64_i8(a[m], b[n], acc[m][n], 0, 0, 0);
  }

  // epilogue: out = (acc + round(bias/s_b)) * s_b, s_b = s_w[col]*s_a
  float s_a = __uint_as_float(*sa_bits) / 127.0f;
  float lmax = 0.f;
#pragma unroll
  for (int n = 0; n < 4; ++n) {
    int col = col0 + wn * 64 + n * 16 + fr;
    float sw = s_w[col];
    float sb = sw * s_a;
    float bint = rintf(bias[col] / sb);
#pragma unroll
    for (int m = 0; m < 4; ++m) {
      int rbase = row0 + wm * 64 + m * 16 + (lane >> 4) * 4;
#pragma unroll
      for (int r = 0; r < 4; ++r) {
        float o = ((float)acc[m][n][r] + bint) * sb;
        out[(size_t)(rbase + r) * DOUT + col] = o;
        lmax = fmaxf(lmax, fabsf(o));
      }
    }
  }
  lmax = wave_max(lmax);
  if (lane == 0) atomicMax(omax_bits, __float_as_uint(lmax));
}

// ---- kernel 5: requantize output in place ----
__global__ void k_requant(float4* __restrict__ out, int n4,
                          const unsigned int* __restrict__ omax_bits) {
  float s_o = __uint_as_float(*omax_bits) / 127.0f;
  int idx = blockIdx.x * blockDim.x + threadIdx.x;
  int stride = gridDim.x * blockDim.x;
  for (int i = idx; i < n4; i += stride) {
    float4 v = out[i];
    v.x = fminf(fmaxf(rintf(v.x / s_o), -127.f), 127.f) * s_o;
    v.y = fminf(fmaxf(rintf(v.y / s_o), -127.f), 127.f) * s_o;
    v.z = fminf(fmaxf(rintf(v.z / s_o), -127.f), 127.f) * s_o;
    v.w = fminf(fmaxf(rintf(v.w / s_o), -127.f), 127.f) * s_o;
    out[i] = v;
  }
}

extern "C" void kernel_launch(void* const* d_in, const int* in_sizes, int n_in,
                              void* d_out, int out_size, void* d_ws,
                              size_t ws_size, hipStream_t stream) {
  const float* x = (const float*)d_in[0];
  const float* w = (const float*)d_in[1];
  const float* bias = (const float*)d_in[2];
  float* out = (float*)d_out;
  char* ws = (char*)d_ws;

  // ws layout:
  //   [0]   uint absmax_x_bits   [4] uint absmax_out_bits
  //   [512] float s_w[DOUT]                    (32 KB)
  //   [65536]                x_int8  (16 MB)
  //   [65536 + B*DIN]        w_int8  (16 MB)
  unsigned int* absbits = (unsigned int*)ws;
  float* s_w = (float*)(ws + 512);
  char* xq = ws + 65536;
  char* wq = ws + 65536 + (size_t)B_DIM * DIN;

  k_init<<<1, 1, 0, stream>>>(absbits);
  k_absmax<<<2048, 256, 0, stream>>>((const float4*)x, B_DIM * DIN / 4, absbits);
  k_quant_x<<<(B_DIM * DIN / 8) / 256, 256, 0, stream>>>(x, (c8*)xq,
                                                         B_DIM * DIN / 8, absbits);
  k_quant_w<<<DOUT, 256, 0, stream>>>(w, (c8*)wq, s_w);
  dim3 grid(DOUT / 128, B_DIM / 128);
  k_gemm<<<grid, 256, 0, stream>>>(xq, wq, s_w, bias, absbits, out, absbits + 1);
  k_requant<<<4096, 256, 0, stream>>>((float4*)out, B_DIM * DOUT / 4, absbits + 1);
}

// Round 2
// 450.307 us; speedup vs baseline: 1.0856x; 1.0856x over previous
//
#include <hip/hip_runtime.h>
#include <stdint.h>

#define B_DIM 8192
#define DIN   2048
#define DOUT  8192
#define NKT   (DIN / 128)  // 16 K-tiles of 128 bytes

typedef int  v4i __attribute__((ext_vector_type(4)));
typedef char c8  __attribute__((ext_vector_type(8)));

__device__ __forceinline__ void gload_lds16(const void* g, void* l) {
  __builtin_amdgcn_global_load_lds(
      (const __attribute__((address_space(1))) void*)g,
      (__attribute__((address_space(3))) void*)l, 16, 0, 0);
}

__device__ __forceinline__ float wave_max(float m) {
#pragma unroll
  for (int off = 32; off; off >>= 1) m = fmaxf(m, __shfl_xor(m, off, 64));
  return m;
}

// ---- kernel 0: zero the two atomic absmax words ----
__global__ void k_init(unsigned int* p) {
  p[0] = 0u;
  p[1] = 0u;
}

// ---- kernel 1: global absmax of x ----
__global__ void k_absmax(const float4* __restrict__ x, int n4,
                         unsigned int* __restrict__ out_bits) {
  int idx = blockIdx.x * blockDim.x + threadIdx.x;
  int stride = gridDim.x * blockDim.x;
  float m = 0.f;
  for (int i = idx; i < n4; i += stride) {
    float4 v = x[i];
    m = fmaxf(m, fabsf(v.x));
    m = fmaxf(m, fabsf(v.y));
    m = fmaxf(m, fabsf(v.z));
    m = fmaxf(m, fabsf(v.w));
  }
  m = wave_max(m);
  if ((threadIdx.x & 63) == 0) atomicMax(out_bits, __float_as_uint(m));
}

// ---- kernel 2: quantize x to int8 (8 elems/thread) ----
__global__ void k_quant_x(const float* __restrict__ x, c8* __restrict__ xq,
                          int n8, const unsigned int* __restrict__ sa_bits) {
  int i = blockIdx.x * blockDim.x + threadIdx.x;
  if (i >= n8) return;
  float s_a = __uint_as_float(*sa_bits) / 127.0f;
  const float4* p = (const float4*)(x + (size_t)i * 8);
  float4 v0 = p[0], v1 = p[1];
  float vv[8] = {v0.x, v0.y, v0.z, v0.w, v1.x, v1.y, v1.z, v1.w};
  c8 q;
#pragma unroll
  for (int j = 0; j < 8; ++j) {
    float r = fminf(fmaxf(rintf(vv[j] / s_a), -127.f), 127.f);
    q[j] = (char)(int)r;
  }
  xq[i] = q;
}

// ---- kernel 3: per-row weight absmax + quantize (1 block / row) ----
__global__ __launch_bounds__(256) void k_quant_w(const float* __restrict__ w,
                                                 c8* __restrict__ wq,
                                                 float* __restrict__ s_w) {
  int row = blockIdx.x;
  int tid = threadIdx.x;
  const float4* wr = (const float4*)(w + (size_t)row * DIN);
  float4 v0 = wr[tid * 2], v1 = wr[tid * 2 + 1];
  float vv[8] = {v0.x, v0.y, v0.z, v0.w, v1.x, v1.y, v1.z, v1.w};
  float m = 0.f;
#pragma unroll
  for (int j = 0; j < 8; ++j) m = fmaxf(m, fabsf(vv[j]));
  m = wave_max(m);
  __shared__ float wmax[4];
  if ((tid & 63) == 0) wmax[tid >> 6] = m;
  __syncthreads();
  m = fmaxf(fmaxf(wmax[0], wmax[1]), fmaxf(wmax[2], wmax[3]));
  float s = m / 127.0f;
  if (tid == 0) s_w[row] = s;
  c8 q;
#pragma unroll
  for (int j = 0; j < 8; ++j) {
    float r = fminf(fmaxf(rintf(vv[j] / s), -127.f), 127.f);
    q[j] = (char)(int)r;
  }
  wq[(size_t)row * (DIN / 8) + tid] = q;
}

// ---- kernel 4: int8 GEMM, 256x256 tile, 8-phase schedule (m201 port) ----
// LDS per slot (2 slots, 64KB each): A [ks][256 rows][64B] at +0 (32KB),
//                                    B [ks][256 rows][64B] at +32768.
// Swizzle: 16B k-slot position p in row r holds global k-slot p ^ (r&3).
__global__ __launch_bounds__(512, 2) void k_gemm8(
    const char* __restrict__ Aq, const char* __restrict__ Bq,
    const float* __restrict__ s_w, const float* __restrict__ bias,
    const unsigned int* __restrict__ sa_bits, float* __restrict__ out,
    unsigned int* __restrict__ omax_bits) {
  __shared__ __align__(16) char lds[131072];

  const int tid = threadIdx.x;
  const int lane = tid & 63;
  const int wave = tid >> 6;
  const int wm = wave >> 2;  // 0..1 (M)
  const int wn = wave & 3;   // 0..3 (N)

  // bijective XCD swizzle (nwg=1024, divisible by 8) + 2D decode
  const int orig = blockIdx.x;
  const int wg = (orig & 7) * (1024 >> 3) + (orig >> 3);
  const int bx = wg & 31;  // col block (DOUT/256)
  const int by = wg >> 5;  // row block (B/256)
  const int row0 = by * 256, col0 = bx * 256;

  // --- staging constants (per thread) ---
  // issue q covers LDS rows q*128 + tid/4, k-slot position tid&3,
  // whose content is global k-slot (tid&3) ^ ((tid/4)&3).
  const int srow = tid >> 2;                               // 0..127
  const int sg = (((tid & 3) ^ ((tid >> 2) & 3)) << 4);    // swizzled src k-byte
  const char* aS = Aq + (size_t)(row0 + srow) * DIN + sg;  // + kt*128 + ks*64
  const char* bS = Bq + (size_t)(col0 + srow) * DIN + sg;

  // --- ds_read constants (per lane) ---
  const int fr = lane & 15;
  const int kbsw = ((lane >> 4) << 4) ^ ((lane & 3) << 4);  // swizzled k-byte
  const int a_base = (wm * 128 + fr) * 64 + kbsw;           // + mh*4096 + mf*1024
  const int b_base = 32768 + (wn * 64 + fr) * 64 + kbsw;    // + nf*1024

  v4i acc[2][4][4];
#pragma unroll
  for (int mh = 0; mh < 2; ++mh)
#pragma unroll
    for (int mf = 0; mf < 4; ++mf)
#pragma unroll
      for (int nf = 0; nf < 4; ++nf) acc[mh][mf][nf] = (v4i){0, 0, 0, 0};

  int h = 0;  // global half-tile issue counter; half order per tile: Ak0,Bk0,Ak1,Bk1
  auto STAGE = [&](int hh) {
    int kt = hh >> 2;
    int slot = kt & 1;
    if (kt >= NKT) kt = 0;  // harmless dummy prefetch (never read)
    int hw = hh & 3;
    const char* src = ((hw & 1) ? bS : aS) + (size_t)kt * 128 + (hw >> 1) * 64;
    int dst = slot * 65536 + (hw & 1) * 32768 + (hw >> 1) * 16384 + tid * 16;
    gload_lds16(src, &lds[dst]);
    gload_lds16(src + (size_t)128 * DIN, &lds[dst + 8192]);
  };

  v4i b_[4];

#define PHASE(SLOT, KS, MH, WAIT)                                           \
  do {                                                                      \
    const int ab = (SLOT) * 65536 + (KS) * 16384 + (MH) * 4096 + a_base;    \
    v4i a_[4];                                                              \
    _Pragma("unroll") for (int mf = 0; mf < 4; ++mf)                        \
        a_[mf] = *(const v4i*)&lds[ab + mf * 1024];                         \
    if (!(MH)) {                                                            \
      const int bb = (SLOT) * 65536 + (KS) * 16384 + b_base;                \
      _Pragma("unroll") for (int nf = 0; nf < 4; ++nf)                      \
          b_[nf] = *(const v4i*)&lds[bb + nf * 1024];                       \
    }                                                                       \
    STAGE(h);                                                               \
    ++h;                                                                    \
    if (WAIT) asm volatile("s_waitcnt vmcnt(6)" ::: "memory");              \
    asm volatile("s_barrier" ::: "memory");                                 \
    __builtin_amdgcn_s_setprio(1);                                          \
    _Pragma("unroll") for (int mf = 0; mf < 4; ++mf)                        \
        _Pragma("unroll") for (int nf = 0; nf < 4; ++nf) acc[MH][mf][nf] =  \
        __builtin_amdgcn_mfma_i32_16x16x64_i8(a_[mf], b_[nf],               \
                                              acc[MH][mf][nf], 0, 0, 0);    \
    __builtin_amdgcn_s_setprio(0);                                          \
    asm volatile("s_barrier" ::: "memory");                                 \
  } while (0)

  // prologue: stage tile0 (4 halves) + tile1's first 3 halves; wait tile0
  STAGE(0); STAGE(1); STAGE(2); STAGE(3); STAGE(4); STAGE(5); STAGE(6);
  h = 7;
  asm volatile("s_waitcnt vmcnt(6)" ::: "memory");
  asm volatile("s_barrier" ::: "memory");

#pragma unroll 1
  for (int it = 0; it < NKT / 2; ++it) {
    PHASE(0, 0, 0, false);  // tile 2it   (slot0), k-step0, M-half0 (reads B)
    PHASE(0, 0, 1, false);
    PHASE(0, 1, 0, false);
    PHASE(0, 1, 1, true);   // phase 4: vmcnt(6) -> tile 2it+1 resident
    PHASE(1, 0, 0, false);  // tile 2it+1 (slot1)
    PHASE(1, 0, 1, false);
    PHASE(1, 1, 0, false);
    PHASE(1, 1, 1, true);   // phase 8: vmcnt(6) -> tile 2it+2 resident
  }
#undef PHASE

  // epilogue: out = (acc + round(bias/s_b)) * s_b, s_b = s_w[col]*s_a
  float s_a = __uint_as_float(*sa_bits) / 127.0f;
  float lmax = 0.f;
#pragma unroll
  for (int nf = 0; nf < 4; ++nf) {
    int col = col0 + wn * 64 + nf * 16 + fr;
    float sw = s_w[col];
    float sb = sw * s_a;
    float bint = rintf(bias[col] / sb);
#pragma unroll
    for (int mh = 0; mh < 2; ++mh)
#pragma unroll
      for (int mf = 0; mf < 4; ++mf) {
        int rbase = row0 + wm * 128 + mh * 64 + mf * 16 + (lane >> 4) * 4;
#pragma unroll
        for (int r = 0; r < 4; ++r) {
          float o = ((float)acc[mh][mf][nf][r] + bint) * sb;
          out[(size_t)(rbase + r) * DOUT + col] = o;
          lmax = fmaxf(lmax, fabsf(o));
        }
      }
  }
  lmax = wave_max(lmax);
  if (lane == 0) atomicMax(omax_bits, __float_as_uint(lmax));
}

// ---- kernel 5: requantize output in place ----
__global__ void k_requant(float4* __restrict__ out, int n4,
                          const unsigned int* __restrict__ omax_bits) {
  float s_o = __uint_as_float(*omax_bits) / 127.0f;
  int idx = blockIdx.x * blockDim.x + threadIdx.x;
  int stride = gridDim.x * blockDim.x;
  for (int i = idx; i < n4; i += stride) {
    float4 v = out[i];
    v.x = fminf(fmaxf(rintf(v.x / s_o), -127.f), 127.f) * s_o;
    v.y = fminf(fmaxf(rintf(v.y / s_o), -127.f), 127.f) * s_o;
    v.z = fminf(fmaxf(rintf(v.z / s_o), -127.f), 127.f) * s_o;
    v.w = fminf(fmaxf(rintf(v.w / s_o), -127.f), 127.f) * s_o;
    out[i] = v;
  }
}

extern "C" void kernel_launch(void* const* d_in, const int* in_sizes, int n_in,
                              void* d_out, int out_size, void* d_ws,
                              size_t ws_size, hipStream_t stream) {
  const float* x = (const float*)d_in[0];
  const float* w = (const float*)d_in[1];
  const float* bias = (const float*)d_in[2];
  float* out = (float*)d_out;
  char* ws = (char*)d_ws;

  // ws layout:
  //   [0]   uint absmax_x_bits   [4] uint absmax_out_bits
  //   [512] float s_w[DOUT]                    (32 KB)
  //   [65536]                x_int8  (16 MB)
  //   [65536 + B*DIN]        w_int8  (16 MB)
  unsigned int* absbits = (unsigned int*)ws;
  float* s_w = (float*)(ws + 512);
  char* xq = ws + 65536;
  char* wq = ws + 65536 + (size_t)B_DIM * DIN;

  k_init<<<1, 1, 0, stream>>>(absbits);
  k_absmax<<<2048, 256, 0, stream>>>((const float4*)x, B_DIM * DIN / 4, absbits);
  k_quant_x<<<(B_DIM * DIN / 8) / 256, 256, 0, stream>>>(x, (c8*)xq,
                                                         B_DIM * DIN / 8, absbits);
  k_quant_w<<<DOUT, 256, 0, stream>>>(w, (c8*)wq, s_w);
  k_gemm8<<<1024, 512, 0, stream>>>(xq, wq, s_w, bias, absbits, out, absbits + 1);
  k_requant<<<4096, 256, 0, stream>>>((float4*)out, B_DIM * DOUT / 4, absbits + 1);
}